// Round 4
// baseline (349.658 us; speedup 1.0000x reference)
//
#include <hip/hip_runtime.h>

#define NB 8
#define NC 21
#define HW (512 * 512)
#define THREADS 256
#define PX_PER_THREAD 16
#define PIX_PER_BLOCK (THREADS * PX_PER_THREAD)      // 4096
#define BLOCKS_PER_SAMPLE (HW / PIX_PER_BLOCK)       // 64 -> grid 512

// R2/R3 evidence: duration pinned at 120us across 8/16/21 waves per CU ->
// not latency-bound; effective read BW stuck at 2.9 TB/s -> DRAM-pattern
// wall from ~40K concurrent 4KB streams. This version: 16KB contiguous
// bursts per (block, channel), pred phase then targ phase (21 streams per
// block at a time), 512 blocks total.
__global__ __launch_bounds__(THREADS, 2) void conf_kernel(
    const float* __restrict__ pred,
    const float* __restrict__ targ,
    int* __restrict__ conf /* [NB][NC][NC] */) {
  __shared__ int lconf[NC * NC];
  const int tid = threadIdx.x;
  for (int i = tid; i < NC * NC; i += THREADS) lconf[i] = 0;
  __syncthreads();

  const int b   = blockIdx.x / BLOCKS_PER_SAMPLE;
  const int blk = blockIdx.x % BLOCKS_PER_SAMPLE;
  const size_t P0 = (size_t)blk * PIX_PER_BLOCK;
  const float* __restrict__ pplane = pred + (size_t)b * NC * HW + P0;
  const float* __restrict__ tplane = targ + (size_t)b * NC * HW + P0;

  int idp[PX_PER_THREAD];  // predicted class per pixel
  int idt[PX_PER_THREAD];  // true class per pixel

  // ---- phase 1: pred argmax over channels ----
  {
    float4 m[4];
#pragma unroll
    for (int j = 0; j < 4; ++j) {
      m[j] = *(const float4*)(pplane + (size_t)(j * THREADS + tid) * 4);
      idp[4 * j + 0] = 0; idp[4 * j + 1] = 0;
      idp[4 * j + 2] = 0; idp[4 * j + 3] = 0;
    }
#pragma unroll
    for (int c = 1; c < NC; ++c) {
      const float* __restrict__ pc = pplane + (size_t)c * HW;
#pragma unroll
      for (int j = 0; j < 4; ++j) {
        float4 v = *(const float4*)(pc + (size_t)(j * THREADS + tid) * 4);
        if (v.x > m[j].x) { m[j].x = v.x; idp[4 * j + 0] = c; }
        if (v.y > m[j].y) { m[j].y = v.y; idp[4 * j + 1] = c; }
        if (v.z > m[j].z) { m[j].z = v.z; idp[4 * j + 2] = c; }
        if (v.w > m[j].w) { m[j].w = v.w; idp[4 * j + 3] = c; }
      }
    }
  }

  // ---- phase 2: targ argmax over channels ----
  {
    float4 m[4];
#pragma unroll
    for (int j = 0; j < 4; ++j) {
      m[j] = *(const float4*)(tplane + (size_t)(j * THREADS + tid) * 4);
      idt[4 * j + 0] = 0; idt[4 * j + 1] = 0;
      idt[4 * j + 2] = 0; idt[4 * j + 3] = 0;
    }
#pragma unroll
    for (int c = 1; c < NC; ++c) {
      const float* __restrict__ tc = tplane + (size_t)c * HW;
#pragma unroll
      for (int j = 0; j < 4; ++j) {
        float4 v = *(const float4*)(tc + (size_t)(j * THREADS + tid) * 4);
        if (v.x > m[j].x) { m[j].x = v.x; idt[4 * j + 0] = c; }
        if (v.y > m[j].y) { m[j].y = v.y; idt[4 * j + 1] = c; }
        if (v.z > m[j].z) { m[j].z = v.z; idt[4 * j + 2] = c; }
        if (v.w > m[j].w) { m[j].w = v.w; idt[4 * j + 3] = c; }
      }
    }
  }

  // ---- phase 3: accumulate confusion matrix ----
#pragma unroll
  for (int k = 0; k < PX_PER_THREAD; ++k) {
    atomicAdd(&lconf[idt[k] * NC + idp[k]], 1);
  }
  __syncthreads();

  int* __restrict__ gconf = conf + b * NC * NC;
  for (int i = tid; i < NC * NC; i += THREADS) {
    int v = lconf[i];
    if (v) atomicAdd(&gconf[i], v);
  }
}

// Kernel 2: conf -> per-class IoU -> per-sample mean over valid classes ->
// batch mean scalar.
__global__ __launch_bounds__(256) void iou_kernel(const int* __restrict__ conf,
                                                  float* __restrict__ out) {
  __shared__ float iou_sum[NB];
  __shared__ int valid_cnt[NB];
  const int tid = threadIdx.x;
  if (tid < NB) { iou_sum[tid] = 0.f; valid_cnt[tid] = 0; }
  __syncthreads();

  if (tid < NB * NC) {
    const int b = tid / NC, c = tid % NC;
    const int* __restrict__ m = conf + b * NC * NC;
    const int tp = m[c * NC + c];
    int row = 0, col = 0;
#pragma unroll
    for (int j = 0; j < NC; ++j) {
      row += m[c * NC + j];  // TP + FN
      col += m[j * NC + c];  // TP + FP
    }
    if (tp > 0) {
      const float denom = (float)(row + col - tp);  // TP + FN + FP
      atomicAdd(&iou_sum[b], (float)tp / denom);
      atomicAdd(&valid_cnt[b], 1);
    }
  }
  __syncthreads();

  if (tid == 0) {
    float s = 0.f;
    for (int b = 0; b < NB; ++b) {
      const int n = valid_cnt[b] > 0 ? valid_cnt[b] : 1;
      s += iou_sum[b] / (float)n;
    }
    out[0] = s / (float)NB;
  }
}

extern "C" void kernel_launch(void* const* d_in, const int* in_sizes, int n_in,
                              void* d_out, int out_size, void* d_ws, size_t ws_size,
                              hipStream_t stream) {
  const float* pred = (const float*)d_in[0];
  const float* targ = (const float*)d_in[1];
  float* out = (float*)d_out;
  int* conf = (int*)d_ws;  // NB*NC*NC ints = 14112 B

  hipMemsetAsync(conf, 0, NB * NC * NC * sizeof(int), stream);
  conf_kernel<<<NB * BLOCKS_PER_SAMPLE, THREADS, 0, stream>>>(pred, targ, conf);
  iou_kernel<<<1, 256, 0, stream>>>(conf, out);
}